// Round 5
// baseline (10670.325 us; speedup 1.0000x reference)
//
#include <hip/hip_runtime.h>
#include <hip/hip_bf16.h>

typedef __attribute__((ext_vector_type(8))) short bf16x8;
typedef __attribute__((ext_vector_type(4))) float f32x4;

#define HID 1024
#define BATCH 32
#define NACT (BATCH * HID)        // 32768
#define NWIH (3 * 3 * HID * HID)  // 9,437,184  plane stride (all layers)
#define LSTRIDE (3 * HID * HID)   // per-layer offset within a plane
#define NFC (2500 * HID)          // 2,560,000
#define WXN (HID * HID)           // 1,048,576
#define TSTEPS 64
#define NBLK 64

__device__ __forceinline__ f32x4 mfma16(bf16x8 a, bf16x8 b, f32x4 c) {
  return __builtin_amdgcn_mfma_f32_16x16x32_bf16(a, b, c, 0, 0, 0);
}
__device__ __forceinline__ float bfbits2f(unsigned short u) {
  return __uint_as_float(((unsigned int)u) << 16);
}
__device__ __forceinline__ unsigned short f2bf_rn(float v) {
  union { __hip_bfloat16 b; unsigned short s; } cv;
  cv.b = __float2bfloat16(v);
  return cv.s;
}
// exact 3-way split: 8+8+8 mantissa bits (trunc, trunc, RN)
__device__ __forceinline__ void split3(float v, unsigned short& s0, unsigned short& s1,
                                       unsigned short& s2) {
  s0 = (unsigned short)(__float_as_uint(v) >> 16);
  float r1 = v - bfbits2f(s0);
  s1 = (unsigned short)(__float_as_uint(r1) >> 16);
  float r2 = r1 - bfbits2f(s1);
  s2 = f2bf_rn(r2);
}
__device__ __forceinline__ void split2(float v, unsigned short& s0, unsigned short& s1) {
  s0 = (unsigned short)(__float_as_uint(v) >> 16);
  s1 = f2bf_rn(v - bfbits2f(s0));
}
// coherent (agent/MALL) 16B activation load as 2x 8B relaxed atomics
__device__ __forceinline__ bf16x8 ld_act16(const unsigned short* p) {
  union { unsigned long long u[2]; bf16x8 v; } cv;
  cv.u[0] = __hip_atomic_load((unsigned long long*)p, __ATOMIC_RELAXED, __HIP_MEMORY_SCOPE_AGENT);
  cv.u[1] = __hip_atomic_load((unsigned long long*)p + 1, __ATOMIC_RELAXED, __HIP_MEMORY_SCOPE_AGENT);
  return cv.v;
}
// paired-lane packed plane store (even col lane stores {j, j+1} as one uint, agent scope)
__device__ __forceinline__ void pst_plane(unsigned short* plane, int eidx, unsigned short s,
                                          int colpar) {
  int other = __shfl_xor((int)(unsigned int)s, 1, 64);
  unsigned int packed = ((unsigned int)s) | (((unsigned int)(unsigned short)other) << 16);
  if (!colpar)
    __hip_atomic_store((unsigned int*)(plane + eidx), packed, __ATOMIC_RELAXED,
                       __HIP_MEMORY_SCOPE_AGENT);
}

// ---------------- one-time kernels ----------------
__global__ void convert_weights(const float* __restrict__ Wih, const float* __restrict__ Whh,
                                const float* __restrict__ fcw, unsigned short* __restrict__ WIHP,
                                unsigned short* __restrict__ WHHP, unsigned short* __restrict__ FCWP) {
  int i0 = blockIdx.x * blockDim.x + threadIdx.x;
  int st = gridDim.x * blockDim.x;
  for (int i = i0; i < NWIH; i += st) {
    unsigned short a0, a1, a2, b0, b1, b2;
    split3(Wih[i], a0, a1, a2);
    split3(Whh[i], b0, b1, b2);
    WIHP[i] = a0; WIHP[NWIH + i] = a1; WIHP[2 * NWIH + i] = a2;
    WHHP[i] = b0; WHHP[NWIH + i] = b1; WHHP[2 * NWIH + i] = b2;
  }
  for (int i = i0; i < NFC; i += st) {
    unsigned short c0, c1;
    split2(fcw[i], c0, c1);
    FCWP[i] = c0; FCWP[NFC + i] = c1;
  }
}

__global__ void k_trig(float* __restrict__ cA, float* __restrict__ sA) {
  int i = blockIdx.x * blockDim.x + threadIdx.x;
  if (i < 32 * 50) {
    int a = i / 50, n = i % 50;
    int ka = (a + 34) % 50;  // fftshift+crop row map
    int ph = (ka * n) % 50;
    float ang = 6.283185307179586f * (float)ph / 50.0f;
    cA[i] = cosf(ang);
    sA[i] = sinf(ang);
  }
}

// P[k][n1][c] = sum_n2 fcw[n1*50+n2][k]*cA[c,n2]; Q with sA. 1024*50*32 outputs.
__global__ void k_pq(const float* __restrict__ fcw, const float* __restrict__ cA,
                     const float* __restrict__ sA, float* __restrict__ P, float* __restrict__ Q) {
  int i = blockIdx.x * blockDim.x + threadIdx.x;  // 1,638,400
  if (i >= 1024 * 50 * 32) return;
  int c = i & 31, n1 = (i >> 5) % 50, k = i / (32 * 50);
  float p = 0.f, q = 0.f;
  for (int n2 = 0; n2 < 50; ++n2) {
    float w = fcw[(n1 * 50 + n2) * HID + k];
    p += w * cA[c * 50 + n2];
    q += w * sA[c * 50 + n2];
  }
  P[i] = p;
  Q[i] = q;
}

// W_x[j=a*32+c][k] = sum_n1 cA[a,n1]*P[k][n1][c] - sA[a,n1]*Q[k][n1][c]; split to 3 planes.
__global__ void k_wx(const float* __restrict__ P, const float* __restrict__ Q,
                     const float* __restrict__ cA, const float* __restrict__ sA,
                     unsigned short* __restrict__ WXP) {
  int i = blockIdx.x * blockDim.x + threadIdx.x;  // 1,048,576
  if (i >= WXN) return;
  int j = i >> 10, k = i & 1023;  // note: j-major over threads for coalesced P? keep simple
  int a = j >> 5, c = j & 31;
  float acc = 0.f;
  for (int n1 = 0; n1 < 50; ++n1)
    acc += cA[a * 50 + n1] * P[(k * 50 + n1) * 32 + c] - sA[a * 50 + n1] * Q[(k * 50 + n1) * 32 + c];
  unsigned short s0, s1, s2;
  split3(acc, s0, s1, s2);
  WXP[j * HID + k] = s0;
  WXP[WXN + j * HID + k] = s1;
  WXP[2 * WXN + j * HID + k] = s2;
}

__global__ void k_cx(const float* __restrict__ fcb, const float* __restrict__ cA,
                     const float* __restrict__ sA, float* __restrict__ CXV) {
  int j = blockIdx.x * blockDim.x + threadIdx.x;
  if (j >= HID) return;
  int a = j >> 5, c = j & 31;
  float acc = 0.f;
  for (int n1 = 0; n1 < 50; ++n1)
    for (int n2 = 0; n2 < 50; ++n2)
      acc += fcb[n1 * 50 + n2] * (cA[a * 50 + n1] * cA[c * 50 + n2] - sA[a * 50 + n1] * sA[c * 50 + n2]);
  CXV[j] = acc;
}

__global__ void setup_kernel(const float* __restrict__ x_in, float* __restrict__ H,
                             unsigned short* __restrict__ HBP, unsigned short* __restrict__ XBP,
                             unsigned long long* __restrict__ barcnt) {
  int i0 = blockIdx.x * blockDim.x + threadIdx.x;
  int st = gridDim.x * blockDim.x;
  if (i0 == 0) *barcnt = 0ull;
  for (int k = i0; k < 3 * NACT; k += st) H[k] = 0.0f;             // fp32 set 0
  for (int k = i0; k < 3 * 3 * NACT; k += st) HBP[k] = 0;          // planes set 0
  for (int k = i0; k < NACT; k += st) {
    unsigned short s0, s1, s2;
    split3(x_in[k], s0, s1, s2);
    XBP[k] = s0; XBP[NACT + k] = s1; XBP[2 * NACT + k] = s2;
  }
}

// ---------------- grid barrier: relaxed agent atomics, NO cache invalidation ----------------
__device__ __forceinline__ void gbar(unsigned long long* cnt, unsigned long long tgt) {
  __syncthreads();  // compiler emits s_waitcnt vmcnt(0) before s_barrier -> sc1 stores MALL-visible
  if (threadIdx.x == 0) {
    __atomic_signal_fence(__ATOMIC_SEQ_CST);
    __hip_atomic_fetch_add(cnt, 1ull, __ATOMIC_RELAXED, __HIP_MEMORY_SCOPE_AGENT);
    while (__hip_atomic_load(cnt, __ATOMIC_RELAXED, __HIP_MEMORY_SCOPE_AGENT) < tgt)
      __builtin_amdgcn_s_sleep(1);
    __atomic_signal_fence(__ATOMIC_SEQ_CST);
  }
  __syncthreads();
}

// ---------------- persistent: 64 steps x (L0,L1,L2 GRU + X feedback) ----------------
__global__ __launch_bounds__(256) void rnn_persistent(
    const unsigned short* __restrict__ WIHP, const unsigned short* __restrict__ WHHP,
    const unsigned short* __restrict__ WXP,
    const float* __restrict__ b_ih, const float* __restrict__ b_hh, const float* __restrict__ CXV,
    float* __restrict__ H,          // [2][3][NACT] fp32 (block-private slices)
    unsigned short* __restrict__ HBP,  // [2][3][3planes][NACT] shared via sc1
    unsigned short* __restrict__ XBP,  // [3planes][NACT] shared via sc1
    unsigned short* __restrict__ HIST0, unsigned short* __restrict__ HIST1,  // [2048][1024]
    unsigned long long* __restrict__ barcnt) {
  __shared__ float smem[9216];
  const int tid = threadIdx.x;
  const int L = tid & 63, w = tid >> 6;
  const int col = L & 15, quad = L >> 4;
  const int kb = w * 256, aoff = quad * 8;
  const int bid = blockIdx.x;
  const int jt = bid * 16;
  const int colpar = col & 1;
  const f32x4 zero = {0.f, 0.f, 0.f, 0.f};
  unsigned long long tgt = 0;

#pragma unroll 1
  for (int t = 0; t < TSTEPS; ++t) {
    const int pi = t & 1, po = pi ^ 1;
#pragma unroll 1
    for (int l = 0; l < 3; ++l) {
      const unsigned short* Wih = WIHP + (size_t)l * LSTRIDE;
      const unsigned short* Whh = WHHP + (size_t)l * LSTRIDE;
      const unsigned short* Ain = (l == 0) ? XBP : (HBP + (size_t)((po * 3 + (l - 1)) * 3) * NACT);
      const unsigned short* hb_in = HBP + (size_t)((pi * 3 + l) * 3) * NACT;
      const float* h_in = H + (size_t)(pi * 3 + l) * NACT;
      float* h_out = H + (size_t)(po * 3 + l) * NACT;
      unsigned short* hb_out = HBP + (size_t)((po * 3 + l) * 3) * NACT;
      const float* bih = b_ih + l * 3 * HID;
      const float* bhh = b_hh + l * 3 * HID;

      f32x4 accI[3][2], accH[3][2];
#pragma unroll
      for (int g = 0; g < 3; ++g)
#pragma unroll
        for (int mh = 0; mh < 2; ++mh) { accI[g][mh] = zero; accH[g][mh] = zero; }

      for (int it = 0; it < 8; ++it) {
        int k0 = kb + it * 32 + aoff;
        bf16x8 xa[3][2], ha[3][2], bi[3][3], bh[3][3];
#pragma unroll
        for (int mh = 0; mh < 2; ++mh) {
          int r = (mh * 16 + col) * HID + k0;
#pragma unroll
          for (int p = 0; p < 3; ++p) {
            xa[p][mh] = ld_act16(Ain + p * NACT + r);
            ha[p][mh] = ld_act16(hb_in + p * NACT + r);
          }
        }
#pragma unroll
        for (int g = 0; g < 3; ++g) {
          int rr = (g * HID + jt + col) * HID + k0;
#pragma unroll
          for (int p = 0; p < 3; ++p) {
            bi[p][g] = *(const bf16x8*)(Wih + (size_t)p * NWIH + rr);
            bh[p][g] = *(const bf16x8*)(Whh + (size_t)p * NWIH + rr);
          }
        }
#pragma unroll
        for (int g = 0; g < 3; ++g)
#pragma unroll
          for (int mh = 0; mh < 2; ++mh)
#pragma unroll
            for (int p = 0; p < 3; ++p)
#pragma unroll
              for (int q = 0; q < 3 - p; ++q) {
                accI[g][mh] = mfma16(xa[p][mh], bi[q][g], accI[g][mh]);
                accH[g][mh] = mfma16(ha[p][mh], bh[q][g], accH[g][mh]);
              }
      }

      if (w > 0) {
        float* p = &smem[((w - 1) * 64 + L) * 48];
#pragma unroll
        for (int g = 0; g < 3; ++g)
#pragma unroll
          for (int mh = 0; mh < 2; ++mh) {
            *(f32x4*)(p + (g * 2 + mh) * 4) = accI[g][mh];
            *(f32x4*)(p + 24 + (g * 2 + mh) * 4) = accH[g][mh];
          }
      }
      __syncthreads();
      if (w == 0) {
#pragma unroll
        for (int s = 0; s < 3; ++s) {
          const float* p = &smem[(s * 64 + L) * 48];
#pragma unroll
          for (int g = 0; g < 3; ++g)
#pragma unroll
            for (int mh = 0; mh < 2; ++mh) {
              accI[g][mh] += *(const f32x4*)(p + (g * 2 + mh) * 4);
              accH[g][mh] += *(const f32x4*)(p + 24 + (g * 2 + mh) * 4);
            }
        }
        int j = jt + col;
        float bI[3], bH[3];
#pragma unroll
        for (int g = 0; g < 3; ++g) { bI[g] = bih[g * HID + j]; bH[g] = bhh[g * HID + j]; }
#pragma unroll
        for (int mh = 0; mh < 2; ++mh) {
#pragma unroll
          for (int r = 0; r < 4; ++r) {
            int b = mh * 16 + quad * 4 + r;
            float ir = accI[0][mh][r] + bI[0];
            float iz = accI[1][mh][r] + bI[1];
            float in_ = accI[2][mh][r] + bI[2];
            float hr = accH[0][mh][r] + bH[0];
            float hz = accH[1][mh][r] + bH[1];
            float hn = accH[2][mh][r] + bH[2];
            float rr = 1.0f / (1.0f + expf(-(ir + hr)));
            float zz = 1.0f / (1.0f + expf(-(iz + hz)));
            float nn = tanhf(in_ + rr * hn);
            float hnew = (1.0f - zz) * nn + zz * h_in[b * HID + j];
            h_out[b * HID + j] = hnew;  // private to this block: plain
            unsigned short s0, s1, s2;
            split3(hnew, s0, s1, s2);
            int eidx = b * HID + j;
            pst_plane(hb_out, eidx, s0, colpar);
            pst_plane(hb_out + NACT, eidx, s1, colpar);
            pst_plane(hb_out + 2 * NACT, eidx, s2, colpar);
            if (l == 2) {  // h2 history for deferred output GEMM (plain, post-kernel consumer)
              HIST0[(size_t)(t * BATCH + b) * HID + j] = s0;
              HIST1[(size_t)(t * BATCH + b) * HID + j] = s1;
            }
          }
        }
      }
      tgt += NBLK;
      gbar(barcnt, tgt);
    }

    // ---------- X phase: x_next = h2 . W_x + c_x (composed FC+DFT feedback) ----------
    if (t < TSTEPS - 1) {
      const unsigned short* h2p = HBP + (size_t)((po * 3 + 2) * 3) * NACT;
      f32x4 accX[2] = {zero, zero};
      for (int it = 0; it < 8; ++it) {
        int k0 = kb + it * 32 + aoff;
        bf16x8 a0[3], a1[3], bx[3];
#pragma unroll
        for (int p = 0; p < 3; ++p) {
          a0[p] = ld_act16(h2p + p * NACT + col * HID + k0);
          a1[p] = ld_act16(h2p + p * NACT + (16 + col) * HID + k0);
          bx[p] = *(const bf16x8*)(WXP + (size_t)p * WXN + (jt + col) * HID + k0);
        }
#pragma unroll
        for (int p = 0; p < 3; ++p)
#pragma unroll
          for (int q = 0; q < 3 - p; ++q) {
            accX[0] = mfma16(a0[p], bx[q], accX[0]);
            accX[1] = mfma16(a1[p], bx[q], accX[1]);
          }
      }
      __syncthreads();
      if (w > 0) {
        float* p = &smem[((w - 1) * 64 + L) * 8];
        *(f32x4*)p = accX[0];
        *(f32x4*)(p + 4) = accX[1];
      }
      __syncthreads();
      if (w == 0) {
#pragma unroll
        for (int s = 0; s < 3; ++s) {
          const float* p = &smem[(s * 64 + L) * 8];
          accX[0] += *(const f32x4*)p;
          accX[1] += *(const f32x4*)(p + 4);
        }
        int j = jt + col;
        float cx = CXV[j];
#pragma unroll
        for (int mh = 0; mh < 2; ++mh)
#pragma unroll
          for (int r = 0; r < 4; ++r) {
            int b = mh * 16 + quad * 4 + r;
            float xv = accX[mh][r] + cx;
            unsigned short s0, s1, s2;
            split3(xv, s0, s1, s2);
            int eidx = b * HID + j;
            pst_plane(XBP, eidx, s0, colpar);
            pst_plane(XBP + NACT, eidx, s1, colpar);
            pst_plane(XBP + 2 * NACT, eidx, s2, colpar);
          }
      }
      tgt += NBLK;
      gbar(barcnt, tgt);
    }
  }
}

// ---------------- deferred output GEMM: dout[2048][2500] = HIST(2pl) @ FCW(2pl)^T + fcb ----------
__global__ __launch_bounds__(256) void final_fc(const unsigned short* __restrict__ H0,
                                                const unsigned short* __restrict__ H1,
                                                const unsigned short* __restrict__ FCWP,
                                                const float* __restrict__ fcb,
                                                float* __restrict__ dout) {
  int tid = threadIdx.x;
  int L = tid & 63, ws = tid >> 6;
  int col = L & 15, quad = L >> 4;
  int m0 = blockIdx.y * 64 + ws * 16;
  int jt = blockIdx.x * 64;
  f32x4 acc[4];
#pragma unroll
  for (int s = 0; s < 4; ++s) acc[s] = {0.f, 0.f, 0.f, 0.f};
  for (int kt = 0; kt < 32; ++kt) {
    int k0 = kt * 32 + quad * 8;
    bf16x8 ah = *(const bf16x8*)(H0 + (size_t)(m0 + col) * HID + k0);
    bf16x8 am = *(const bf16x8*)(H1 + (size_t)(m0 + col) * HID + k0);
    bf16x8 bh[4], bm[4];
#pragma unroll
    for (int s = 0; s < 4; ++s) {
      int jr = jt + s * 16 + col;
      int rc = jr < 2500 ? jr : 2499;
      bh[s] = *(const bf16x8*)(FCWP + (size_t)rc * HID + k0);
      bm[s] = *(const bf16x8*)(FCWP + (size_t)NFC + (size_t)rc * HID + k0);
    }
#pragma unroll
    for (int s = 0; s < 4; ++s) {
      acc[s] = mfma16(ah, bh[s], acc[s]);
      acc[s] = mfma16(ah, bm[s], acc[s]);
      acc[s] = mfma16(am, bh[s], acc[s]);
    }
  }
#pragma unroll
  for (int s = 0; s < 4; ++s) {
    int j = jt + s * 16 + col;
    if (j < 2500) {
      float bias = fcb[j];
#pragma unroll
      for (int r = 0; r < 4; ++r) {
        int R = m0 + quad * 4 + r;
        dout[(size_t)R * 2500 + j] = acc[s][r] + bias;
      }
    }
  }
}

extern "C" void kernel_launch(void* const* d_in, const int* in_sizes, int n_in,
                              void* d_out, int out_size, void* d_ws, size_t ws_size,
                              hipStream_t stream) {
  const float* x_in = (const float*)d_in[0];
  const float* W_ih = (const float*)d_in[1];
  const float* W_hh = (const float*)d_in[2];
  const float* b_ih = (const float*)d_in[3];
  const float* b_hh = (const float*)d_in[4];
  const float* fc_w = (const float*)d_in[5];
  const float* fc_b = (const float*)d_in[6];
  float* dout = (float*)d_out;
  char* ws = (char*)d_ws;

  // workspace layout (bytes); P/Q overlap HIST (disjoint lifetimes)
  unsigned short* WIHP = (unsigned short*)(ws + 0);            // 56,623,104
  unsigned short* WHHP = (unsigned short*)(ws + 56623104);     // 56,623,104
  unsigned short* FCWP = (unsigned short*)(ws + 113246208);    // 10,240,000 (2 planes)
  unsigned short* WXP  = (unsigned short*)(ws + 123486208);    // 6,291,456 (3 planes)
  float* H             = (float*)(ws + 129777664);             // 786,432
  unsigned short* HBP  = (unsigned short*)(ws + 130564096);    // 1,179,648
  unsigned short* XBP  = (unsigned short*)(ws + 131743744);    // 196,608
  float* CXV           = (float*)(ws + 131940352);             // 4,096
  float* CA            = (float*)(ws + 131944448);             // 6,400
  float* SA            = (float*)(ws + 131950848);             // 6,400
  unsigned long long* BAR = (unsigned long long*)(ws + 131957248);  // 64
  unsigned short* HIST0 = (unsigned short*)(ws + 131957312);   // 4,194,304
  unsigned short* HIST1 = (unsigned short*)(ws + 136151616);   // 4,194,304
  float* Pbuf          = (float*)(ws + 131957312);             // 6,553,600 (overlaps HIST)
  float* Qbuf          = (float*)(ws + 138510912);             // 6,553,600 -> total 145,064,512

  k_trig<<<7, 256, 0, stream>>>(CA, SA);
  k_pq<<<6400, 256, 0, stream>>>(fc_w, CA, SA, Pbuf, Qbuf);
  k_wx<<<4096, 256, 0, stream>>>(Pbuf, Qbuf, CA, SA, WXP);
  k_cx<<<4, 256, 0, stream>>>(fc_b, CA, SA, CXV);
  convert_weights<<<2048, 256, 0, stream>>>(W_ih, W_hh, fc_w, WIHP, WHHP, FCWP);
  setup_kernel<<<512, 256, 0, stream>>>(x_in, H, HBP, XBP, BAR);
  rnn_persistent<<<NBLK, 256, 0, stream>>>(WIHP, WHHP, WXP, b_ih, b_hh, CXV, H, HBP, XBP,
                                           HIST0, HIST1, BAR);
  final_fc<<<dim3(40, 32), 256, 0, stream>>>(HIST0, HIST1, FCWP, fc_b, dout);
}

// Round 6
// 8986.862 us; speedup vs baseline: 1.1873x; 1.1873x over previous
//
#include <hip/hip_runtime.h>
#include <hip/hip_bf16.h>

typedef __attribute__((ext_vector_type(8))) short bf16x8;
typedef __attribute__((ext_vector_type(4))) float f32x4;

#define HID 1024
#define BATCH 32
#define NACT (BATCH * HID)        // 32768
#define NWIH (3 * 3 * HID * HID)  // 9,437,184  plane stride (all layers)
#define LSTRIDE (3 * HID * HID)   // per-layer offset within a plane
#define NFC (2500 * HID)          // 2,560,000
#define WXN (HID * HID)           // 1,048,576
#define G3 (3 * HID)              // 3072
#define TSTEPS 64
#define NBLK 256
#define NTHR 512

__device__ __forceinline__ f32x4 mfma16(bf16x8 a, bf16x8 b, f32x4 c) {
  return __builtin_amdgcn_mfma_f32_16x16x32_bf16(a, b, c, 0, 0, 0);
}
__device__ __forceinline__ float bfbits2f(unsigned short u) {
  return __uint_as_float(((unsigned int)u) << 16);
}
__device__ __forceinline__ unsigned short f2bf_rn(float v) {
  union { __hip_bfloat16 b; unsigned short s; } cv;
  cv.b = __float2bfloat16(v);
  return cv.s;
}
// exact 3-way split of fp32: 8+8+8 mantissa bits (trunc, trunc, RN)
__device__ __forceinline__ void split3(float v, unsigned short& s0, unsigned short& s1,
                                       unsigned short& s2) {
  s0 = (unsigned short)(__float_as_uint(v) >> 16);
  float r1 = v - bfbits2f(s0);
  s1 = (unsigned short)(__float_as_uint(r1) >> 16);
  float r2 = r1 - bfbits2f(s1);
  s2 = f2bf_rn(r2);
}
__device__ __forceinline__ void split2(float v, unsigned short& s0, unsigned short& s1) {
  s0 = (unsigned short)(__float_as_uint(v) >> 16);
  s1 = f2bf_rn(v - bfbits2f(s0));
}
// coherent (agent/MALL) 16B activation load as 2x 8B relaxed atomics
__device__ __forceinline__ bf16x8 ld_act16(const unsigned short* p) {
  union { unsigned long long u[2]; bf16x8 v; } cv;
  cv.u[0] = __hip_atomic_load((unsigned long long*)p, __ATOMIC_RELAXED, __HIP_MEMORY_SCOPE_AGENT);
  cv.u[1] = __hip_atomic_load((unsigned long long*)p + 1, __ATOMIC_RELAXED, __HIP_MEMORY_SCOPE_AGENT);
  return cv.v;
}
__device__ __forceinline__ float ld_f32(const float* p) {
  return __hip_atomic_load(p, __ATOMIC_RELAXED, __HIP_MEMORY_SCOPE_AGENT);
}
__device__ __forceinline__ void st_f32(float* p, float v) {
  __hip_atomic_store(p, v, __ATOMIC_RELAXED, __HIP_MEMORY_SCOPE_AGENT);
}
// paired-lane packed plane store: lanes (even,odd) pack two adjacent j's into one u32
__device__ __forceinline__ void pst_plane(unsigned short* plane, int eidx, unsigned short s,
                                          int par) {
  int other = __shfl_xor((int)(unsigned int)s, 1, 64);
  unsigned int packed = ((unsigned int)s) | (((unsigned int)(unsigned short)other) << 16);
  if (!par)
    __hip_atomic_store((unsigned int*)(plane + eidx), packed, __ATOMIC_RELAXED,
                       __HIP_MEMORY_SCOPE_AGENT);
}

// ---------------- one-time kernels ----------------
__global__ void convert_weights(const float* __restrict__ Wih, const float* __restrict__ Whh,
                                const float* __restrict__ fcw, unsigned short* __restrict__ WIHP,
                                unsigned short* __restrict__ WHHP, unsigned short* __restrict__ FCWP) {
  int i0 = blockIdx.x * blockDim.x + threadIdx.x;
  int st = gridDim.x * blockDim.x;
  for (int i = i0; i < NWIH; i += st) {
    unsigned short a0, a1, a2, b0, b1, b2;
    split3(Wih[i], a0, a1, a2);
    split3(Whh[i], b0, b1, b2);
    WIHP[i] = a0; WIHP[NWIH + i] = a1; WIHP[2 * NWIH + i] = a2;
    WHHP[i] = b0; WHHP[NWIH + i] = b1; WHHP[2 * NWIH + i] = b2;
  }
  for (int i = i0; i < NFC; i += st) {
    unsigned short c0, c1;
    split2(fcw[i], c0, c1);
    FCWP[i] = c0; FCWP[NFC + i] = c1;
  }
}

__global__ void k_trig(float* __restrict__ cA, float* __restrict__ sA) {
  int i = blockIdx.x * blockDim.x + threadIdx.x;
  if (i < 32 * 50) {
    int a = i / 50, n = i % 50;
    int ka = (a + 34) % 50;  // fftshift+crop row map
    int ph = (ka * n) % 50;  // exact integer angle reduction
    float ang = 6.283185307179586f * (float)ph / 50.0f;
    cA[i] = cosf(ang);
    sA[i] = sinf(ang);
  }
}

// chunked (k in [k0,k0+512)): P[kk][n1][c], Q likewise
__global__ void k_pq(const float* __restrict__ fcw, const float* __restrict__ cA,
                     const float* __restrict__ sA, float* __restrict__ P, float* __restrict__ Q,
                     int k0) {
  int i = blockIdx.x * blockDim.x + threadIdx.x;  // 512*50*32 = 819,200
  if (i >= 512 * 50 * 32) return;
  int c = i & 31, n1 = (i >> 5) % 50, kk = i / (32 * 50);
  float p = 0.f, q = 0.f;
  for (int n2 = 0; n2 < 50; ++n2) {
    float w = fcw[(n1 * 50 + n2) * HID + k0 + kk];
    p += w * cA[c * 50 + n2];
    q += w * sA[c * 50 + n2];
  }
  P[i] = p;
  Q[i] = q;
}

// W_x[j][k]: composed FC+DFT feedback; 3-plane split, chunked over k
__global__ void k_wx(const float* __restrict__ P, const float* __restrict__ Q,
                     const float* __restrict__ cA, const float* __restrict__ sA,
                     unsigned short* __restrict__ WXP, int k0) {
  int i = blockIdx.x * blockDim.x + threadIdx.x;  // 1024*512
  if (i >= 1024 * 512) return;
  int kk = i & 511, j = i >> 9;
  int a = j >> 5, c = j & 31;
  float acc = 0.f;
  for (int n1 = 0; n1 < 50; ++n1)
    acc += cA[a * 50 + n1] * P[kk * 1600 + n1 * 32 + c] - sA[a * 50 + n1] * Q[kk * 1600 + n1 * 32 + c];
  unsigned short s0, s1, s2;
  split3(acc, s0, s1, s2);
  int idx = j * HID + k0 + kk;
  WXP[idx] = s0;
  WXP[WXN + idx] = s1;
  WXP[2 * WXN + idx] = s2;
}

__global__ void k_cx(const float* __restrict__ fcb, const float* __restrict__ cA,
                     const float* __restrict__ sA, float* __restrict__ CXV) {
  int j = blockIdx.x * blockDim.x + threadIdx.x;
  if (j >= HID) return;
  int a = j >> 5, c = j & 31;
  float acc = 0.f;
  for (int n1 = 0; n1 < 50; ++n1)
    for (int n2 = 0; n2 < 50; ++n2)
      acc += fcb[n1 * 50 + n2] * (cA[a * 50 + n1] * cA[c * 50 + n2] - sA[a * 50 + n1] * sA[c * 50 + n2]);
  CXV[j] = acc;
}

__global__ void setup_state(const float* __restrict__ x_in, float* __restrict__ H,
                            unsigned short* __restrict__ HBP, unsigned short* __restrict__ XBP,
                            unsigned long long* __restrict__ barcnt) {
  int i0 = blockIdx.x * blockDim.x + threadIdx.x;
  int st = gridDim.x * blockDim.x;
  if (i0 == 0) *barcnt = 0ull;
  for (int k = i0; k < 3 * NACT; k += st) H[k] = 0.0f;
  for (int k = i0; k < 3 * 3 * NACT; k += st) HBP[k] = 0;
  for (int k = i0; k < NACT; k += st) {
    unsigned short s0, s1, s2;
    split3(x_in[k], s0, s1, s2);
    XBP[k] = s0; XBP[NACT + k] = s1; XBP[2 * NACT + k] = s2;
  }
}

// ---------------- grid barrier (relaxed agent atomics; stores drained by __syncthreads) ----------
__device__ __forceinline__ void gbar(unsigned long long* cnt, unsigned long long tgt) {
  __syncthreads();
  if (threadIdx.x == 0) {
    __atomic_signal_fence(__ATOMIC_SEQ_CST);
    __hip_atomic_fetch_add(cnt, 1ull, __ATOMIC_RELAXED, __HIP_MEMORY_SCOPE_AGENT);
    while (__hip_atomic_load(cnt, __ATOMIC_RELAXED, __HIP_MEMORY_SCOPE_AGENT) < tgt)
      __builtin_amdgcn_s_sleep(2);
    __atomic_signal_fence(__ATOMIC_SEQ_CST);
  }
  __syncthreads();
}

// ---------------- shared GEMM tile: 32(batch) x 16(features), K=1024 split over 8 waves --------
// 3-plane x 3-plane emulated-fp32 (pairs p+q<=2). Result valid in wave 0 after reduce.
__device__ __forceinline__ void gemm_reduce(const unsigned short* __restrict__ Bp, long bplane,
                                            const unsigned short* __restrict__ Ap, int gfbase,
                                            float* smem, f32x4 acc[2]) {
  const int tid = threadIdx.x;
  const int L = tid & 63, w = tid >> 6;
  const int col = L & 15, quad = L >> 4;
  acc[0] = {0.f, 0.f, 0.f, 0.f};
  acc[1] = {0.f, 0.f, 0.f, 0.f};
  const unsigned short* brow = Bp + (size_t)(gfbase + col) * HID;
  for (int it = 0; it < 4; ++it) {
    int k0 = w * 128 + it * 32 + quad * 8;
    bf16x8 a[3][2], b[3];
#pragma unroll
    for (int mh = 0; mh < 2; ++mh) {
      int r = (mh * 16 + col) * HID + k0;
#pragma unroll
      for (int p = 0; p < 3; ++p) a[p][mh] = ld_act16(Ap + (size_t)p * NACT + r);
    }
#pragma unroll
    for (int p = 0; p < 3; ++p) b[p] = *(const bf16x8*)(brow + (size_t)p * bplane + k0);
#pragma unroll
    for (int p = 0; p < 3; ++p)
#pragma unroll
      for (int q = 0; q < 3 - p; ++q)
#pragma unroll
        for (int mh = 0; mh < 2; ++mh) acc[mh] = mfma16(a[p][mh], b[q], acc[mh]);
  }
  __syncthreads();  // previous smem consumers done
  if (w > 0) {
    float* s = smem + ((w - 1) * 64 + L) * 8;
    *(f32x4*)s = acc[0];
    *(f32x4*)(s + 4) = acc[1];
  }
  __syncthreads();
  if (w == 0) {
#pragma unroll
    for (int s = 0; s < 7; ++s) {
      const float* p = smem + ((s * 64) + L) * 8;
      acc[0] += *(const f32x4*)p;
      acc[1] += *(const f32x4*)(p + 4);
    }
  }
}

// ---------------- persistent kernel ----------------
__global__ __launch_bounds__(NTHR, 2) void rnn_persistent(
    const unsigned short* __restrict__ WIHP, const unsigned short* __restrict__ WHHP,
    const unsigned short* __restrict__ WXP,
    const float* __restrict__ b_ih, const float* __restrict__ b_hh, const float* __restrict__ CXV,
    float* __restrict__ H,             // [3][NACT] fp32 (owned by P-blocks)
    unsigned short* __restrict__ HBP,  // [3 layers][3 planes][NACT]
    unsigned short* __restrict__ XBP,  // [3 planes][NACT]
    float* __restrict__ GH,            // [3][32][3072]
    float* __restrict__ GI,            // [32][3072]
    unsigned short* __restrict__ HIST0, unsigned short* __restrict__ HIST1,  // [2048][1024]
    unsigned long long* __restrict__ barcnt) {
  __shared__ float smem[3584];
  const int tid = threadIdx.x;
  const int L = tid & 63, w = tid >> 6;
  const int col = L & 15, quad = L >> 4;
  const int bid = blockIdx.x;
  unsigned long long tgt = 0;

#pragma unroll 1
  for (int t = 0; t < TSTEPS; ++t) {
    // ===== Phase A: gh0,gh1,gh2 (vs h_{t-1}) + gi0 (vs x_t) — 768 tasks, 3 per block =====
#pragma unroll 1
    for (int i = 0; i < 3; ++i) {
      int tau = bid + NBLK * i;
      int s = tau / 192, tile = tau % 192;
      int gf = tile * 16;
      const unsigned short* Bp;
      const unsigned short* Ap;
      float* outp;
      if (s < 3) {
        Bp = WHHP + (size_t)s * LSTRIDE;
        Ap = HBP + (size_t)s * 3 * NACT;
        outp = GH + (size_t)s * (32 * G3);
      } else {
        Bp = WIHP;  // layer 0
        Ap = XBP;
        outp = GI;
      }
      f32x4 acc[2];
      gemm_reduce(Bp, NWIH, Ap, gf, smem, acc);
      if (w == 0) {
#pragma unroll
        for (int mh = 0; mh < 2; ++mh)
#pragma unroll
          for (int r = 0; r < 4; ++r) {
            int b = mh * 16 + quad * 4 + r;
            st_f32(outp + (size_t)b * G3 + gf + col, acc[mh][r]);
          }
      }
    }
    tgt += NBLK;
    gbar(barcnt, tgt);

    // ===== serial chain: P0, G1, P1, G2, P2 =====
#pragma unroll 1
    for (int l = 0; l < 3; ++l) {
      // ---- pointwise for layer l (64 blocks, 1 element/thread) ----
      if (bid < 64) {
        int jt = bid * 16;
        int b = tid >> 4, jj = tid & 15, j = jt + jj;
        float gi[3], gh[3];
#pragma unroll
        for (int g = 0; g < 3; ++g) {
          gi[g] = ld_f32(GI + (size_t)b * G3 + g * HID + j);
          gh[g] = ld_f32(GH + (size_t)l * (32 * G3) + (size_t)b * G3 + g * HID + j);
        }
        float ir = gi[0] + b_ih[l * G3 + j];
        float iz = gi[1] + b_ih[l * G3 + HID + j];
        float in_ = gi[2] + b_ih[l * G3 + 2 * HID + j];
        float hr = gh[0] + b_hh[l * G3 + j];
        float hz = gh[1] + b_hh[l * G3 + HID + j];
        float hn = gh[2] + b_hh[l * G3 + 2 * HID + j];
        float rr = 1.0f / (1.0f + expf(-(ir + hr)));
        float zz = 1.0f / (1.0f + expf(-(iz + hz)));
        float nn = tanhf(in_ + rr * hn);
        float hold = H[(size_t)l * NACT + b * HID + j];
        float hnew = (1.0f - zz) * nn + zz * hold;
        H[(size_t)l * NACT + b * HID + j] = hnew;
        unsigned short s0, s1, s2;
        split3(hnew, s0, s1, s2);
        int eidx = b * HID + j;
        unsigned short* hb = HBP + (size_t)l * 3 * NACT;
        int par = tid & 1;
        pst_plane(hb, eidx, s0, par);
        pst_plane(hb + NACT, eidx, s1, par);
        pst_plane(hb + 2 * NACT, eidx, s2, par);
        if (l == 2) {
          HIST0[(size_t)(t * BATCH + b) * HID + j] = s0;
          HIST1[(size_t)(t * BATCH + b) * HID + j] = s1;
        }
      }
      tgt += NBLK;
      gbar(barcnt, tgt);

      // ---- gi for layer l+1 (192 blocks) ----
      if (l < 2) {
        if (bid < 192) {
          int gf = bid * 16;
          f32x4 acc[2];
          gemm_reduce(WIHP + (size_t)(l + 1) * LSTRIDE, NWIH, HBP + (size_t)l * 3 * NACT, gf,
                      smem, acc);
          if (w == 0) {
#pragma unroll
            for (int mh = 0; mh < 2; ++mh)
#pragma unroll
              for (int r = 0; r < 4; ++r) {
                int b = mh * 16 + quad * 4 + r;
                st_f32(GI + (size_t)b * G3 + gf + col, acc[mh][r]);
              }
          }
        }
        tgt += NBLK;
        gbar(barcnt, tgt);
      }
    }

    // ===== X phase: x_{t+1} = h2_t . W_x + c_x (64 blocks) =====
    if (t < TSTEPS - 1) {
      if (bid < 64) {
        int jt = bid * 16;
        f32x4 acc[2];
        gemm_reduce(WXP, WXN, HBP + (size_t)2 * 3 * NACT, jt, smem, acc);
        if (w == 0) {
          int j = jt + col;
          float cx = CXV[j];
          int par = col & 1;
#pragma unroll
          for (int mh = 0; mh < 2; ++mh)
#pragma unroll
            for (int r = 0; r < 4; ++r) {
              int b = mh * 16 + quad * 4 + r;
              float xv = acc[mh][r] + cx;
              unsigned short s0, s1, s2;
              split3(xv, s0, s1, s2);
              int eidx = b * HID + j;
              pst_plane(XBP, eidx, s0, par);
              pst_plane(XBP + NACT, eidx, s1, par);
              pst_plane(XBP + 2 * NACT, eidx, s2, par);
            }
        }
      }
      tgt += NBLK;
      gbar(barcnt, tgt);
    }
  }
}

// ---------------- deferred output GEMM: dout[2048][2500] = HIST(2pl) @ FCW(2pl)^T + fcb --------
__global__ __launch_bounds__(256) void final_fc(const unsigned short* __restrict__ H0,
                                                const unsigned short* __restrict__ H1,
                                                const unsigned short* __restrict__ FCWP,
                                                const float* __restrict__ fcb,
                                                float* __restrict__ dout) {
  int tid = threadIdx.x;
  int L = tid & 63, ws = tid >> 6;
  int col = L & 15, quad = L >> 4;
  int m0 = blockIdx.y * 64 + ws * 16;
  int jt = blockIdx.x * 64;
  f32x4 acc[4];
#pragma unroll
  for (int s = 0; s < 4; ++s) acc[s] = {0.f, 0.f, 0.f, 0.f};
  for (int kt = 0; kt < 32; ++kt) {
    int k0 = kt * 32 + quad * 8;
    bf16x8 ah = *(const bf16x8*)(H0 + (size_t)(m0 + col) * HID + k0);
    bf16x8 am = *(const bf16x8*)(H1 + (size_t)(m0 + col) * HID + k0);
    bf16x8 bh[4], bm[4];
#pragma unroll
    for (int s = 0; s < 4; ++s) {
      int jr = jt + s * 16 + col;
      int rc = jr < 2500 ? jr : 2499;
      bh[s] = *(const bf16x8*)(FCWP + (size_t)rc * HID + k0);
      bm[s] = *(const bf16x8*)(FCWP + (size_t)NFC + (size_t)rc * HID + k0);
    }
#pragma unroll
    for (int s = 0; s < 4; ++s) {
      acc[s] = mfma16(ah, bh[s], acc[s]);
      acc[s] = mfma16(ah, bm[s], acc[s]);
      acc[s] = mfma16(am, bh[s], acc[s]);
    }
  }
#pragma unroll
  for (int s = 0; s < 4; ++s) {
    int j = jt + s * 16 + col;
    if (j < 2500) {
      float bias = fcb[j];
#pragma unroll
      for (int r = 0; r < 4; ++r) {
        int R = m0 + quad * 4 + r;
        dout[(size_t)R * 2500 + j] = acc[s][r] + bias;
      }
    }
  }
}

extern "C" void kernel_launch(void* const* d_in, const int* in_sizes, int n_in,
                              void* d_out, int out_size, void* d_ws, size_t ws_size,
                              hipStream_t stream) {
  const float* x_in = (const float*)d_in[0];
  const float* W_ih = (const float*)d_in[1];
  const float* W_hh = (const float*)d_in[2];
  const float* b_ih = (const float*)d_in[3];
  const float* b_hh = (const float*)d_in[4];
  const float* fc_w = (const float*)d_in[5];
  const float* fc_b = (const float*)d_in[6];
  float* dout = (float*)d_out;
  char* ws = (char*)d_ws;

  // workspace layout (bytes); P/Q chunks overlap HIST (disjoint lifetimes)
  unsigned short* WIHP = (unsigned short*)(ws + 0);            // 56,623,104
  unsigned short* WHHP = (unsigned short*)(ws + 56623104);     // 56,623,104
  unsigned short* FCWP = (unsigned short*)(ws + 113246208);    // 10,240,000 (2 planes)
  unsigned short* WXP  = (unsigned short*)(ws + 123486208);    // 6,291,456 (3 planes)
  float* H             = (float*)(ws + 129777664);             // 393,216
  unsigned short* HBP  = (unsigned short*)(ws + 130170880);    // 589,824
  unsigned short* XBP  = (unsigned short*)(ws + 130760704);    // 196,608
  float* GH            = (float*)(ws + 130957312);             // 1,179,648
  float* GI            = (float*)(ws + 132136960);             // 393,216
  float* CXV           = (float*)(ws + 132530176);             // 4,096
  float* CA            = (float*)(ws + 132534272);             // 6,400
  float* SA            = (float*)(ws + 132540672);             // 6,400
  unsigned long long* BAR = (unsigned long long*)(ws + 132547072);  // 256
  unsigned short* HIST0 = (unsigned short*)(ws + 132547328);   // 4,194,304
  unsigned short* HIST1 = (unsigned short*)(ws + 136741632);   // 4,194,304 -> end 140,935,936
  float* Pbuf          = (float*)(ws + 132547328);             // 3,276,800 (overlaps HIST)
  float* Qbuf          = (float*)(ws + 135824128);             // 3,276,800

  k_trig<<<7, 256, 0, stream>>>(CA, SA);
  for (int k0 = 0; k0 < 1024; k0 += 512) {
    k_pq<<<3200, 256, 0, stream>>>(fc_w, CA, SA, Pbuf, Qbuf, k0);
    k_wx<<<2048, 256, 0, stream>>>(Pbuf, Qbuf, CA, SA, WXP, k0);
  }
  k_cx<<<4, 256, 0, stream>>>(fc_b, CA, SA, CXV);
  convert_weights<<<2048, 256, 0, stream>>>(W_ih, W_hh, fc_w, WIHP, WHHP, FCWP);
  setup_state<<<512, 256, 0, stream>>>(x_in, H, HBP, XBP, BAR);
  rnn_persistent<<<NBLK, NTHR, 0, stream>>>(WIHP, WHHP, WXP, b_ih, b_hh, CXV, H, HBP, XBP,
                                            GH, GI, HIST0, HIST1, BAR);
  final_fc<<<dim3(40, 32), 256, 0, stream>>>(HIST0, HIST1, FCWP, fc_b, dout);
}

// Round 7
// 6899.303 us; speedup vs baseline: 1.5466x; 1.3026x over previous
//
#include <hip/hip_runtime.h>
#include <hip/hip_bf16.h>

typedef __attribute__((ext_vector_type(8))) short bf16x8;
typedef __attribute__((ext_vector_type(4))) float f32x4;

#define HID 1024
#define BATCH 32
#define NACT (BATCH * HID)        // 32768
#define NWIH (3 * 3 * HID * HID)  // 9,437,184  plane stride (all layers)
#define LSTRIDE (3 * HID * HID)   // per-layer offset within a plane
#define NFC (2500 * HID)          // 2,560,000
#define WXN (HID * HID)           // 1,048,576
#define G3 (3 * HID)              // 3072
#define TSTEPS 64
#define NBLK 256
#define NTHR 512
#define FSTRIDE 32                // flag stride in u32 (128 B)

__device__ __forceinline__ f32x4 mfma16(bf16x8 a, bf16x8 b, f32x4 c) {
  return __builtin_amdgcn_mfma_f32_16x16x32_bf16(a, b, c, 0, 0, 0);
}
__device__ __forceinline__ float bfbits2f(unsigned short u) {
  return __uint_as_float(((unsigned int)u) << 16);
}
__device__ __forceinline__ unsigned short f2bf_rn(float v) {
  union { __hip_bfloat16 b; unsigned short s; } cv;
  cv.b = __float2bfloat16(v);
  return cv.s;
}
// exact 3-way split of fp32: 8+8+8 mantissa bits (trunc, trunc, RN)
__device__ __forceinline__ void split3(float v, unsigned short& s0, unsigned short& s1,
                                       unsigned short& s2) {
  s0 = (unsigned short)(__float_as_uint(v) >> 16);
  float r1 = v - bfbits2f(s0);
  s1 = (unsigned short)(__float_as_uint(r1) >> 16);
  float r2 = r1 - bfbits2f(s1);
  s2 = f2bf_rn(r2);
}
__device__ __forceinline__ void split2(float v, unsigned short& s0, unsigned short& s1) {
  s0 = (unsigned short)(__float_as_uint(v) >> 16);
  s1 = f2bf_rn(v - bfbits2f(s0));
}
// coherent (agent/MALL) 16B activation load as 2x 8B relaxed atomics
__device__ __forceinline__ bf16x8 ld_act16(const unsigned short* p) {
  union { unsigned long long u[2]; bf16x8 v; } cv;
  cv.u[0] = __hip_atomic_load((unsigned long long*)p, __ATOMIC_RELAXED, __HIP_MEMORY_SCOPE_AGENT);
  cv.u[1] = __hip_atomic_load((unsigned long long*)p + 1, __ATOMIC_RELAXED, __HIP_MEMORY_SCOPE_AGENT);
  return cv.v;
}
__device__ __forceinline__ float ld_f32(const float* p) {
  return __hip_atomic_load(p, __ATOMIC_RELAXED, __HIP_MEMORY_SCOPE_AGENT);
}
__device__ __forceinline__ void st_f32(float* p, float v) {
  __hip_atomic_store(p, v, __ATOMIC_RELAXED, __HIP_MEMORY_SCOPE_AGENT);
}
// paired-lane packed plane store: lanes (even,odd) pack two adjacent j's into one u32
__device__ __forceinline__ void pst_plane(unsigned short* plane, int eidx, unsigned short s,
                                          int par) {
  int other = __shfl_xor((int)(unsigned int)s, 1, 64);
  unsigned int packed = ((unsigned int)s) | (((unsigned int)(unsigned short)other) << 16);
  if (!par)
    __hip_atomic_store((unsigned int*)(plane + eidx), packed, __ATOMIC_RELAXED,
                       __HIP_MEMORY_SCOPE_AGENT);
}

// ---------------- one-time kernels ----------------
__global__ void convert_weights(const float* __restrict__ Wih, const float* __restrict__ Whh,
                                const float* __restrict__ fcw, unsigned short* __restrict__ WIHP,
                                unsigned short* __restrict__ WHHP, unsigned short* __restrict__ FCWP) {
  int i0 = blockIdx.x * blockDim.x + threadIdx.x;
  int st = gridDim.x * blockDim.x;
  for (int i = i0; i < NWIH; i += st) {
    unsigned short a0, a1, a2, b0, b1, b2;
    split3(Wih[i], a0, a1, a2);
    split3(Whh[i], b0, b1, b2);
    WIHP[i] = a0; WIHP[NWIH + i] = a1; WIHP[2 * NWIH + i] = a2;
    WHHP[i] = b0; WHHP[NWIH + i] = b1; WHHP[2 * NWIH + i] = b2;
  }
  for (int i = i0; i < NFC; i += st) {
    unsigned short c0, c1;
    split2(fcw[i], c0, c1);
    FCWP[i] = c0; FCWP[NFC + i] = c1;
  }
}

__global__ void k_trig(float* __restrict__ cA, float* __restrict__ sA) {
  int i = blockIdx.x * blockDim.x + threadIdx.x;
  if (i < 32 * 50) {
    int a = i / 50, n = i % 50;
    int ka = (a + 34) % 50;  // fftshift+crop row map
    int ph = (ka * n) % 50;  // exact integer angle reduction
    float ang = 6.283185307179586f * (float)ph / 50.0f;
    cA[i] = cosf(ang);
    sA[i] = sinf(ang);
  }
}

// P[(n1*32+c)*512 + kk] for k-chunk [k0, k0+512): coalesced stores over kk.
// grid: 2 k-subchunks x 50 n1 = 100 blocks, 256 threads (kk = sub*256 + tid)
__global__ void k_pq(const float* __restrict__ fcw, const float* __restrict__ cA,
                     const float* __restrict__ sA, float* __restrict__ P, float* __restrict__ Q,
                     int k0) {
  int n1 = blockIdx.x / 2;
  int kk = (blockIdx.x & 1) * 256 + threadIdx.x;
  int k = k0 + kk;
  float accP[32], accQ[32];
#pragma unroll
  for (int c = 0; c < 32; ++c) { accP[c] = 0.f; accQ[c] = 0.f; }
  for (int n2 = 0; n2 < 50; ++n2) {
    float w = fcw[(n1 * 50 + n2) * HID + k];  // coalesced over threads
#pragma unroll
    for (int c = 0; c < 32; ++c) {
      accP[c] = fmaf(w, cA[c * 50 + n2], accP[c]);
      accQ[c] = fmaf(w, sA[c * 50 + n2], accQ[c]);
    }
  }
#pragma unroll
  for (int c = 0; c < 32; ++c) {
    P[(n1 * 32 + c) * 512 + kk] = accP[c];
    Q[(n1 * 32 + c) * 512 + kk] = accQ[c];
  }
}

// W_x[j][k] for k-chunk: grid 1024 blocks (one per j), threads over kk (2 each).
__global__ void k_wx(const float* __restrict__ P, const float* __restrict__ Q,
                     const float* __restrict__ cA, const float* __restrict__ sA,
                     unsigned short* __restrict__ WXP, int k0) {
  int j = blockIdx.x;
  int a = j >> 5, c = j & 31;
  float acc[2] = {0.f, 0.f};
  for (int n1 = 0; n1 < 50; ++n1) {
    float ca = cA[a * 50 + n1], sa = sA[a * 50 + n1];
    int base = (n1 * 32 + c) * 512;
#pragma unroll
    for (int i = 0; i < 2; ++i) {
      int kk = threadIdx.x + 256 * i;
      acc[i] = fmaf(ca, P[base + kk], acc[i]);
      acc[i] = fmaf(-sa, Q[base + kk], acc[i]);
    }
  }
#pragma unroll
  for (int i = 0; i < 2; ++i) {
    int kk = threadIdx.x + 256 * i;
    unsigned short s0, s1, s2;
    split3(acc[i], s0, s1, s2);
    int idx = j * HID + k0 + kk;
    WXP[idx] = s0;
    WXP[WXN + idx] = s1;
    WXP[2 * WXN + idx] = s2;
  }
}

__global__ void k_cx(const float* __restrict__ fcb, const float* __restrict__ cA,
                     const float* __restrict__ sA, float* __restrict__ CXV) {
  int j = blockIdx.x * blockDim.x + threadIdx.x;
  if (j >= HID) return;
  int a = j >> 5, c = j & 31;
  float acc = 0.f;
  for (int n1 = 0; n1 < 50; ++n1)
    for (int n2 = 0; n2 < 50; ++n2)
      acc += fcb[n1 * 50 + n2] * (cA[a * 50 + n1] * cA[c * 50 + n2] - sA[a * 50 + n1] * sA[c * 50 + n2]);
  CXV[j] = acc;
}

__global__ void setup_state(const float* __restrict__ x_in, float* __restrict__ H,
                            unsigned short* __restrict__ HBP, unsigned short* __restrict__ XBP,
                            unsigned int* __restrict__ flags, unsigned int* __restrict__ rel) {
  int i0 = blockIdx.x * blockDim.x + threadIdx.x;
  int st = gridDim.x * blockDim.x;
  for (int k = i0; k < NBLK * FSTRIDE; k += st) flags[k] = 0u;
  if (i0 == 0) *rel = 0u;
  for (int k = i0; k < 3 * NACT; k += st) H[k] = 0.0f;
  for (int k = i0; k < 3 * 3 * NACT; k += st) HBP[k] = 0;
  for (int k = i0; k < NACT; k += st) {
    unsigned short s0, s1, s2;
    split3(x_in[k], s0, s1, s2);
    XBP[k] = s0; XBP[NACT + k] = s1; XBP[2 * NACT + k] = s2;
  }
}

// ---------------- grid barrier v2: parallel flag stores + master gather + release ----------
__device__ __forceinline__ void gbar(unsigned int* flags, unsigned int* rel, unsigned int e) {
  __syncthreads();  // drains vmcnt(0): all this block's agent stores are MALL-visible
  const int tid = threadIdx.x;
  const int bid = blockIdx.x;
  if (tid == 0)
    __hip_atomic_store(flags + bid * FSTRIDE, e, __ATOMIC_RELAXED, __HIP_MEMORY_SCOPE_AGENT);
  if (bid == 0) {
    if (tid < 64) {
      for (;;) {
        bool ok = true;
#pragma unroll
        for (int i = 0; i < 4; ++i) {
          unsigned int v = __hip_atomic_load(flags + (tid + 64 * i) * FSTRIDE, __ATOMIC_RELAXED,
                                             __HIP_MEMORY_SCOPE_AGENT);
          ok &= (v >= e);
        }
        if (__all(ok)) break;
        __builtin_amdgcn_s_sleep(1);
      }
      if (tid == 0)
        __hip_atomic_store(rel, e, __ATOMIC_RELAXED, __HIP_MEMORY_SCOPE_AGENT);
    }
  } else if (tid == 0) {
    while (__hip_atomic_load(rel, __ATOMIC_RELAXED, __HIP_MEMORY_SCOPE_AGENT) < e)
      __builtin_amdgcn_s_sleep(1);
  }
  __syncthreads();
}

// ---------------- shared GEMM tile: 32(batch) x 16(features), K=1024 split over 8 waves --------
__device__ __forceinline__ void gemm_reduce(const unsigned short* __restrict__ Bp, long bplane,
                                            const unsigned short* __restrict__ Ap, int gfbase,
                                            float* smem, f32x4 acc[2]) {
  const int tid = threadIdx.x;
  const int L = tid & 63, w = tid >> 6;
  const int col = L & 15, quad = L >> 4;
  acc[0] = {0.f, 0.f, 0.f, 0.f};
  acc[1] = {0.f, 0.f, 0.f, 0.f};
  const unsigned short* brow = Bp + (size_t)(gfbase + col) * HID;
  for (int it = 0; it < 4; ++it) {
    int k0 = w * 128 + it * 32 + quad * 8;
    bf16x8 a[3][2], b[3];
#pragma unroll
    for (int mh = 0; mh < 2; ++mh) {
      int r = (mh * 16 + col) * HID + k0;
#pragma unroll
      for (int p = 0; p < 3; ++p) a[p][mh] = ld_act16(Ap + (size_t)p * NACT + r);
    }
#pragma unroll
    for (int p = 0; p < 3; ++p) b[p] = *(const bf16x8*)(brow + (size_t)p * bplane + k0);
#pragma unroll
    for (int p = 0; p < 3; ++p)
#pragma unroll
      for (int q = 0; q < 3 - p; ++q)
#pragma unroll
        for (int mh = 0; mh < 2; ++mh) acc[mh] = mfma16(a[p][mh], b[q], acc[mh]);
  }
  __syncthreads();  // previous smem consumers done
  if (w > 0) {
    float* s = smem + ((w - 1) * 64 + L) * 8;
    *(f32x4*)s = acc[0];
    *(f32x4*)(s + 4) = acc[1];
  }
  __syncthreads();
  if (w == 0) {
#pragma unroll
    for (int s = 0; s < 7; ++s) {
      const float* p = smem + ((s * 64) + L) * 8;
      acc[0] += *(const f32x4*)p;
      acc[1] += *(const f32x4*)(p + 4);
    }
  }
}

// ---------------- persistent kernel ----------------
__global__ __launch_bounds__(NTHR, 2) void rnn_persistent(
    const unsigned short* __restrict__ WIHP, const unsigned short* __restrict__ WHHP,
    const unsigned short* __restrict__ WXP,
    const float* __restrict__ b_ih, const float* __restrict__ b_hh, const float* __restrict__ CXV,
    float* __restrict__ H,             // [3][NACT] fp32 (block-private slices)
    unsigned short* __restrict__ HBP,  // [3 layers][3 planes][NACT]
    unsigned short* __restrict__ XBP,  // [3 planes][NACT]
    float* __restrict__ GH,            // [3][32][3072]
    float* __restrict__ GI,            // [32][3072]
    unsigned short* __restrict__ HIST0, unsigned short* __restrict__ HIST1,  // [2048][1024]
    unsigned int* __restrict__ FLAGS, unsigned int* __restrict__ REL) {
  __shared__ float smem[3584];
  const int tid = threadIdx.x;
  const int L = tid & 63, w = tid >> 6;
  const int col = L & 15, quad = L >> 4;
  const int bid = blockIdx.x;
  unsigned int ep = 0;

#pragma unroll 1
  for (int t = 0; t < TSTEPS; ++t) {
    // ===== Phase A: gh0,gh1,gh2 (vs h_{t-1}) + gi0 (vs x_t) — 768 tasks, 3 per block =====
#pragma unroll 1
    for (int i = 0; i < 3; ++i) {
      int tau = bid + NBLK * i;
      int s = tau / 192, tile = tau % 192;
      int gf = tile * 16;
      const unsigned short* Bp;
      const unsigned short* Ap;
      float* outp;
      if (s < 3) {
        Bp = WHHP + (size_t)s * LSTRIDE;
        Ap = HBP + (size_t)s * 3 * NACT;
        outp = GH + (size_t)s * (32 * G3);
      } else {
        Bp = WIHP;  // layer 0
        Ap = XBP;
        outp = GI;
      }
      f32x4 acc[2];
      gemm_reduce(Bp, NWIH, Ap, gf, smem, acc);
      if (w == 0) {
#pragma unroll
        for (int mh = 0; mh < 2; ++mh)
#pragma unroll
          for (int r = 0; r < 4; ++r) {
            int b = mh * 16 + quad * 4 + r;
            st_f32(outp + (size_t)b * G3 + gf + col, acc[mh][r]);
          }
      }
    }
    gbar(FLAGS, REL, ++ep);

    // ===== serial chain: P0, G1, P1, G2, P2 =====
#pragma unroll 1
    for (int l = 0; l < 3; ++l) {
      // ---- pointwise for layer l (64 blocks, 1 element/thread) ----
      if (bid < 64) {
        int jt = bid * 16;
        int b = tid >> 4, jj = tid & 15, j = jt + jj;
        float gi[3], gh[3];
#pragma unroll
        for (int g = 0; g < 3; ++g) {
          gi[g] = ld_f32(GI + (size_t)b * G3 + g * HID + j);
          gh[g] = ld_f32(GH + (size_t)l * (32 * G3) + (size_t)b * G3 + g * HID + j);
        }
        float ir = gi[0] + b_ih[l * G3 + j];
        float iz = gi[1] + b_ih[l * G3 + HID + j];
        float in_ = gi[2] + b_ih[l * G3 + 2 * HID + j];
        float hr = gh[0] + b_hh[l * G3 + j];
        float hz = gh[1] + b_hh[l * G3 + HID + j];
        float hn = gh[2] + b_hh[l * G3 + 2 * HID + j];
        float rr = 1.0f / (1.0f + expf(-(ir + hr)));
        float zz = 1.0f / (1.0f + expf(-(iz + hz)));
        float nn = tanhf(in_ + rr * hn);
        float hold = H[(size_t)l * NACT + b * HID + j];
        float hnew = (1.0f - zz) * nn + zz * hold;
        H[(size_t)l * NACT + b * HID + j] = hnew;
        unsigned short s0, s1, s2;
        split3(hnew, s0, s1, s2);
        int eidx = b * HID + j;
        unsigned short* hb = HBP + (size_t)l * 3 * NACT;
        int par = tid & 1;
        pst_plane(hb, eidx, s0, par);
        pst_plane(hb + NACT, eidx, s1, par);
        pst_plane(hb + 2 * NACT, eidx, s2, par);
        if (l == 2) {
          HIST0[(size_t)(t * BATCH + b) * HID + j] = s0;
          HIST1[(size_t)(t * BATCH + b) * HID + j] = s1;
        }
      }
      gbar(FLAGS, REL, ++ep);

      // ---- gi for layer l+1 (192 blocks) ----
      if (l < 2) {
        if (bid < 192) {
          int gf = bid * 16;
          f32x4 acc[2];
          gemm_reduce(WIHP + (size_t)(l + 1) * LSTRIDE, NWIH, HBP + (size_t)l * 3 * NACT, gf,
                      smem, acc);
          if (w == 0) {
#pragma unroll
            for (int mh = 0; mh < 2; ++mh)
#pragma unroll
              for (int r = 0; r < 4; ++r) {
                int b = mh * 16 + quad * 4 + r;
                st_f32(GI + (size_t)b * G3 + gf + col, acc[mh][r]);
              }
          }
        }
        gbar(FLAGS, REL, ++ep);
      }
    }

    // ===== X phase: x_{t+1} = h2_t . W_x + c_x (64 blocks) =====
    if (t < TSTEPS - 1) {
      if (bid < 64) {
        int jt = bid * 16;
        f32x4 acc[2];
        gemm_reduce(WXP, WXN, HBP + (size_t)2 * 3 * NACT, jt, smem, acc);
        if (w == 0) {
          int j = jt + col;
          float cx = CXV[j];
          int par = col & 1;
#pragma unroll
          for (int mh = 0; mh < 2; ++mh)
#pragma unroll
            for (int r = 0; r < 4; ++r) {
              int b = mh * 16 + quad * 4 + r;
              float xv = acc[mh][r] + cx;
              unsigned short s0, s1, s2;
              split3(xv, s0, s1, s2);
              int eidx = b * HID + j;
              pst_plane(XBP, eidx, s0, par);
              pst_plane(XBP + NACT, eidx, s1, par);
              pst_plane(XBP + 2 * NACT, eidx, s2, par);
            }
        }
      }
      gbar(FLAGS, REL, ++ep);
    }
  }
}

// ---------------- deferred output GEMM: dout[2048][2500] = HIST(2pl) @ FCW(2pl)^T + fcb --------
__global__ __launch_bounds__(256) void final_fc(const unsigned short* __restrict__ H0,
                                                const unsigned short* __restrict__ H1,
                                                const unsigned short* __restrict__ FCWP,
                                                const float* __restrict__ fcb,
                                                float* __restrict__ dout) {
  int tid = threadIdx.x;
  int L = tid & 63, ws = tid >> 6;
  int col = L & 15, quad = L >> 4;
  int m0 = blockIdx.y * 64 + ws * 16;
  int jt = blockIdx.x * 64;
  f32x4 acc[4];
#pragma unroll
  for (int s = 0; s < 4; ++s) acc[s] = {0.f, 0.f, 0.f, 0.f};
  for (int kt = 0; kt < 32; ++kt) {
    int k0 = kt * 32 + quad * 8;
    bf16x8 ah = *(const bf16x8*)(H0 + (size_t)(m0 + col) * HID + k0);
    bf16x8 am = *(const bf16x8*)(H1 + (size_t)(m0 + col) * HID + k0);
    bf16x8 bh[4], bm[4];
#pragma unroll
    for (int s = 0; s < 4; ++s) {
      int jr = jt + s * 16 + col;
      int rc = jr < 2500 ? jr : 2499;
      bh[s] = *(const bf16x8*)(FCWP + (size_t)rc * HID + k0);
      bm[s] = *(const bf16x8*)(FCWP + (size_t)NFC + (size_t)rc * HID + k0);
    }
#pragma unroll
    for (int s = 0; s < 4; ++s) {
      acc[s] = mfma16(ah, bh[s], acc[s]);
      acc[s] = mfma16(ah, bm[s], acc[s]);
      acc[s] = mfma16(am, bh[s], acc[s]);
    }
  }
#pragma unroll
  for (int s = 0; s < 4; ++s) {
    int j = jt + s * 16 + col;
    if (j < 2500) {
      float bias = fcb[j];
#pragma unroll
      for (int r = 0; r < 4; ++r) {
        int R = m0 + quad * 4 + r;
        dout[(size_t)R * 2500 + j] = acc[s][r] + bias;
      }
    }
  }
}

extern "C" void kernel_launch(void* const* d_in, const int* in_sizes, int n_in,
                              void* d_out, int out_size, void* d_ws, size_t ws_size,
                              hipStream_t stream) {
  const float* x_in = (const float*)d_in[0];
  const float* W_ih = (const float*)d_in[1];
  const float* W_hh = (const float*)d_in[2];
  const float* b_ih = (const float*)d_in[3];
  const float* b_hh = (const float*)d_in[4];
  const float* fc_w = (const float*)d_in[5];
  const float* fc_b = (const float*)d_in[6];
  float* dout = (float*)d_out;
  char* ws = (char*)d_ws;

  // workspace layout (bytes); P/Q chunks overlap HIST (disjoint lifetimes)
  unsigned short* WIHP = (unsigned short*)(ws + 0);            // 56,623,104
  unsigned short* WHHP = (unsigned short*)(ws + 56623104);     // 56,623,104
  unsigned short* FCWP = (unsigned short*)(ws + 113246208);    // 10,240,000 (2 planes)
  unsigned short* WXP  = (unsigned short*)(ws + 123486208);    // 6,291,456 (3 planes)
  float* H             = (float*)(ws + 129777664);             // 393,216
  unsigned short* HBP  = (unsigned short*)(ws + 130170880);    // 589,824
  unsigned short* XBP  = (unsigned short*)(ws + 130760704);    // 196,608
  float* GH            = (float*)(ws + 130957312);             // 1,179,648
  float* GI            = (float*)(ws + 132136960);             // 393,216
  float* CXV           = (float*)(ws + 132530176);             // 4,096
  float* CA            = (float*)(ws + 132534272);             // 6,400
  float* SA            = (float*)(ws + 132540672);             // 6,400
  unsigned short* HIST0 = (unsigned short*)(ws + 132547328);   // 4,194,304
  unsigned short* HIST1 = (unsigned short*)(ws + 136741632);   // 4,194,304 -> end 140,935,936
  unsigned int* FLAGS  = (unsigned int*)(ws + 140935936);      // 32,768 (256 x 128B)
  unsigned int* REL    = (unsigned int*)(ws + 140968704);      // 128 -> end 140,968,832
  float* Pbuf          = (float*)(ws + 132547328);             // 3,276,800 (overlaps HIST)
  float* Qbuf          = (float*)(ws + 135824128);             // 3,276,800

  k_trig<<<7, 256, 0, stream>>>(CA, SA);
  for (int k0 = 0; k0 < 1024; k0 += 512) {
    k_pq<<<100, 256, 0, stream>>>(fc_w, CA, SA, Pbuf, Qbuf, k0);
    k_wx<<<1024, 256, 0, stream>>>(Pbuf, Qbuf, CA, SA, WXP, k0);
  }
  k_cx<<<4, 256, 0, stream>>>(fc_b, CA, SA, CXV);
  convert_weights<<<2048, 256, 0, stream>>>(W_ih, W_hh, fc_w, WIHP, WHHP, FCWP);
  setup_state<<<512, 256, 0, stream>>>(x_in, H, HBP, XBP, FLAGS, REL);
  rnn_persistent<<<NBLK, NTHR, 0, stream>>>(WIHP, WHHP, WXP, b_ih, b_hh, CXV, H, HBP, XBP,
                                            GH, GI, HIST0, HIST1, FLAGS, REL);
  final_fc<<<dim3(40, 32), 256, 0, stream>>>(HIST0, HIST1, FCWP, fc_b, dout);
}

// Round 8
// 5705.712 us; speedup vs baseline: 1.8701x; 1.2092x over previous
//
#include <hip/hip_runtime.h>
#include <hip/hip_bf16.h>

typedef __attribute__((ext_vector_type(8))) short bf16x8;
typedef __attribute__((ext_vector_type(4))) float f32x4;

#define HID 1024
#define BATCH 32
#define NACT (BATCH * HID)        // 32768
#define NWIH (3 * 3 * HID * HID)  // 9,437,184  plane stride (all layers)
#define LSTRIDE (3 * HID * HID)   // per-layer offset within a plane
#define NFC (2500 * HID)          // 2,560,000
#define WXN (HID * HID)           // 1,048,576
#define WXIN (3 * HID * HID)      // 3,145,728 (3072x1024)
#define G3 (3 * HID)              // 3072
#define TSTEPS 64
#define NBLK 256
#define NTHR 512
#define FSTRIDE 32

__device__ __forceinline__ f32x4 mfma16(bf16x8 a, bf16x8 b, f32x4 c) {
  return __builtin_amdgcn_mfma_f32_16x16x32_bf16(a, b, c, 0, 0, 0);
}
__device__ __forceinline__ float bfbits2f(unsigned short u) {
  return __uint_as_float(((unsigned int)u) << 16);
}
__device__ __forceinline__ unsigned short f2bf_rn(float v) {
  union { __hip_bfloat16 b; unsigned short s; } cv;
  cv.b = __float2bfloat16(v);
  return cv.s;
}
// exact 3-way split of fp32: 8+8+8 mantissa bits (trunc, trunc, RN)
__device__ __forceinline__ void split3(float v, unsigned short& s0, unsigned short& s1,
                                       unsigned short& s2) {
  s0 = (unsigned short)(__float_as_uint(v) >> 16);
  float r1 = v - bfbits2f(s0);
  s1 = (unsigned short)(__float_as_uint(r1) >> 16);
  float r2 = r1 - bfbits2f(s1);
  s2 = f2bf_rn(r2);
}
__device__ __forceinline__ void split2(float v, unsigned short& s0, unsigned short& s1) {
  s0 = (unsigned short)(__float_as_uint(v) >> 16);
  s1 = f2bf_rn(v - bfbits2f(s0));
}
// coherent (agent/MALL) 16B activation load as 2x 8B relaxed atomics
__device__ __forceinline__ bf16x8 ld_act16(const unsigned short* p) {
  union { unsigned long long u[2]; bf16x8 v; } cv;
  cv.u[0] = __hip_atomic_load((unsigned long long*)p, __ATOMIC_RELAXED, __HIP_MEMORY_SCOPE_AGENT);
  cv.u[1] = __hip_atomic_load((unsigned long long*)p + 1, __ATOMIC_RELAXED, __HIP_MEMORY_SCOPE_AGENT);
  return cv.v;
}
__device__ __forceinline__ float ld_f32(const float* p) {
  return __hip_atomic_load(p, __ATOMIC_RELAXED, __HIP_MEMORY_SCOPE_AGENT);
}
__device__ __forceinline__ void st_f32(float* p, float v) {
  __hip_atomic_store(p, v, __ATOMIC_RELAXED, __HIP_MEMORY_SCOPE_AGENT);
}
// paired-lane packed plane store: (even,odd) lanes pack adjacent j's into one u32
__device__ __forceinline__ void pst_plane(unsigned short* plane, int eidx, unsigned short s,
                                          int par) {
  int other = __shfl_xor((int)(unsigned int)s, 1, 64);
  unsigned int packed = ((unsigned int)s) | (((unsigned int)(unsigned short)other) << 16);
  if (!par)
    __hip_atomic_store((unsigned int*)(plane + eidx), packed, __ATOMIC_RELAXED,
                       __HIP_MEMORY_SCOPE_AGENT);
}

// ---------------- one-time kernels ----------------
__global__ void convert_weights(const float* __restrict__ Wih, const float* __restrict__ Whh,
                                unsigned short* __restrict__ WIHP, unsigned short* __restrict__ WHHP) {
  int i0 = blockIdx.x * blockDim.x + threadIdx.x;
  int st = gridDim.x * blockDim.x;
  for (int i = i0; i < NWIH; i += st) {
    unsigned short a0, a1, a2, b0, b1, b2;
    split3(Wih[i], a0, a1, a2);
    split3(Whh[i], b0, b1, b2);
    WIHP[i] = a0; WIHP[NWIH + i] = a1; WIHP[2 * NWIH + i] = a2;
    WHHP[i] = b0; WHHP[NWIH + i] = b1; WHHP[2 * NWIH + i] = b2;
  }
}

__global__ void convert_fcw(const float* __restrict__ fcw, unsigned short* __restrict__ FCWP) {
  int i0 = blockIdx.x * blockDim.x + threadIdx.x;
  int st = gridDim.x * blockDim.x;
  for (int i = i0; i < NFC; i += st) {
    unsigned short c0, c1;
    split2(fcw[i], c0, c1);
    FCWP[i] = c0; FCWP[NFC + i] = c1;
  }
}

__global__ void k_trig(float* __restrict__ cA, float* __restrict__ sA) {
  int i = blockIdx.x * blockDim.x + threadIdx.x;
  if (i < 32 * 50) {
    int a = i / 50, n = i % 50;
    int ka = (a + 34) % 50;  // fftshift+crop row map
    int ph = (ka * n) % 50;  // exact integer angle reduction
    float ang = 6.283185307179586f * (float)ph / 50.0f;
    cA[i] = cosf(ang);
    sA[i] = sinf(ang);
  }
}

// P[(n1*32+c)*256 + kk] for h-chunk [k0,k0+256)
__global__ void k_pq(const float* __restrict__ fcw, const float* __restrict__ cA,
                     const float* __restrict__ sA, float* __restrict__ P, float* __restrict__ Q,
                     int k0) {
  int n1 = blockIdx.x;
  int kk = threadIdx.x;
  int k = k0 + kk;
  float accP[32], accQ[32];
#pragma unroll
  for (int c = 0; c < 32; ++c) { accP[c] = 0.f; accQ[c] = 0.f; }
  for (int n2 = 0; n2 < 50; ++n2) {
    float w = fcw[(n1 * 50 + n2) * HID + k];
#pragma unroll
    for (int c = 0; c < 32; ++c) {
      accP[c] = fmaf(w, cA[c * 50 + n2], accP[c]);
      accQ[c] = fmaf(w, sA[c * 50 + n2], accQ[c]);
    }
  }
#pragma unroll
  for (int c = 0; c < 32; ++c) {
    P[(n1 * 32 + c) * 256 + kk] = accP[c];
    Q[(n1 * 32 + c) * 256 + kk] = accQ[c];
  }
}

// WxF[f][h] fp32 for h-chunk
__global__ void k_wx(const float* __restrict__ P, const float* __restrict__ Q,
                     const float* __restrict__ cA, const float* __restrict__ sA,
                     float* __restrict__ WxF, int k0) {
  int j = blockIdx.x;  // x feature f
  int a = j >> 5, c = j & 31;
  int kk = threadIdx.x;
  float acc = 0.f;
  for (int n1 = 0; n1 < 50; ++n1) {
    int base = (n1 * 32 + c) * 256 + kk;
    acc = fmaf(cA[a * 50 + n1], P[base], acc);
    acc = fmaf(-sA[a * 50 + n1], Q[base], acc);
  }
  WxF[j * HID + k0 + kk] = acc;
}

// transpose WxF[f][h] -> WXTP planes [h][f] (3-plane exact)
__global__ void k_transpose(const float* __restrict__ WxF, unsigned short* __restrict__ WXTP) {
  __shared__ float lds[64][65];
  int f0 = blockIdx.x * 64, h0 = blockIdx.y * 64;
  for (int idx = threadIdx.x; idx < 4096; idx += 256) {
    int r = idx >> 6, c = idx & 63;
    lds[r][c] = WxF[(f0 + r) * HID + h0 + c];
  }
  __syncthreads();
  for (int idx = threadIdx.x; idx < 4096; idx += 256) {
    int r = idx >> 6, c = idx & 63;  // r = h-local, c = f-local
    unsigned short s0, s1, s2;
    split3(lds[c][r], s0, s1, s2);
    int o = (h0 + r) * HID + f0 + c;
    WXTP[o] = s0; WXTP[WXN + o] = s1; WXTP[2 * WXN + o] = s2;
  }
}

// compose: WXI[g][h] = sum_f Wih0[g][f] * Wx[f][h]; inputs exact 3-plane, output 2-plane
__global__ __launch_bounds__(256) void k_compose(const unsigned short* __restrict__ WIHP,
                                                 const unsigned short* __restrict__ WXTP,
                                                 unsigned short* __restrict__ WXIP) {
  int tid = threadIdx.x;
  int L = tid & 63, ws = tid >> 6;
  int col = L & 15, quad = L >> 4;
  int m0 = blockIdx.y * 64 + ws * 16;  // g strip
  int jt = blockIdx.x * 64;            // h tile
  f32x4 acc[4];
#pragma unroll
  for (int s = 0; s < 4; ++s) acc[s] = {0.f, 0.f, 0.f, 0.f};
  for (int kt = 0; kt < 32; ++kt) {
    int k0 = kt * 32 + quad * 8;
    bf16x8 a[3], b[3][4];
#pragma unroll
    for (int p = 0; p < 3; ++p)
      a[p] = *(const bf16x8*)(WIHP + (size_t)p * NWIH + (m0 + col) * HID + k0);
#pragma unroll
    for (int s = 0; s < 4; ++s)
#pragma unroll
      for (int p = 0; p < 3; ++p)
        b[p][s] = *(const bf16x8*)(WXTP + (size_t)p * WXN + (jt + s * 16 + col) * HID + k0);
#pragma unroll
    for (int p = 0; p < 3; ++p)
#pragma unroll
      for (int q = 0; q < 3; ++q)
        if (p + q <= 2)
#pragma unroll
          for (int s = 0; s < 4; ++s) acc[s] = mfma16(a[q], b[p][s], acc[s]);
  }
#pragma unroll
  for (int s = 0; s < 4; ++s) {
    int h = jt + s * 16 + col;
#pragma unroll
    for (int r = 0; r < 4; ++r) {
      int g = m0 + quad * 4 + r;
      unsigned short s0, s1;
      split2(acc[s][r], s0, s1);
      WXIP[(size_t)g * HID + h] = s0;
      WXIP[(size_t)WXIN + (size_t)g * HID + h] = s1;
    }
  }
}

__global__ void k_cx(const float* __restrict__ fcb, const float* __restrict__ cA,
                     const float* __restrict__ sA, float* __restrict__ CXV) {
  int j = blockIdx.x * blockDim.x + threadIdx.x;
  if (j >= HID) return;
  int a = j >> 5, c = j & 31;
  float acc = 0.f;
  for (int n1 = 0; n1 < 50; ++n1)
    for (int n2 = 0; n2 < 50; ++n2)
      acc += fcb[n1 * 50 + n2] * (cA[a * 50 + n1] * cA[c * 50 + n2] - sA[a * 50 + n1] * sA[c * 50 + n2]);
  CXV[j] = acc;
}

// BIH0C[g] = b_ih0[g] + sum_k CXV[k] * Wih0[g][k]
__global__ void k_bih0c(const float* __restrict__ b_ih, const float* __restrict__ CXV,
                        const float* __restrict__ Wih, float* __restrict__ BIH0C) {
  __shared__ float red[256];
  int g = blockIdx.x;
  float p = 0.f;
  for (int k = threadIdx.x; k < HID; k += 256) p = fmaf(CXV[k], Wih[(size_t)g * HID + k], p);
  red[threadIdx.x] = p;
  __syncthreads();
  for (int s = 128; s > 0; s >>= 1) {
    if (threadIdx.x < s) red[threadIdx.x] += red[threadIdx.x + s];
    __syncthreads();
  }
  if (threadIdx.x == 0) BIH0C[g] = b_ih[g] + red[0];
}

__global__ void setup_state(const float* __restrict__ x_in, float* __restrict__ H,
                            unsigned short* __restrict__ HBP, unsigned short* __restrict__ XBP,
                            unsigned int* __restrict__ flags, unsigned int* __restrict__ rel) {
  int i0 = blockIdx.x * blockDim.x + threadIdx.x;
  int st = gridDim.x * blockDim.x;
  for (int k = i0; k < NBLK * FSTRIDE; k += st) flags[k] = 0u;
  if (i0 == 0) *rel = 0u;
  for (int k = i0; k < 3 * NACT; k += st) H[k] = 0.0f;
  for (int k = i0; k < 3 * 3 * NACT; k += st) HBP[k] = 0;
  for (int k = i0; k < NACT; k += st) {
    unsigned short s0, s1, s2;
    split3(x_in[k], s0, s1, s2);
    XBP[k] = s0; XBP[NACT + k] = s1; XBP[2 * NACT + k] = s2;
  }
}

// ---------------- grid barrier: parallel flags + master gather + release ----------------
__device__ __forceinline__ void gbar(unsigned int* flags, unsigned int* rel, unsigned int e) {
  __syncthreads();
  const int tid = threadIdx.x;
  const int bid = blockIdx.x;
  if (tid == 0)
    __hip_atomic_store(flags + bid * FSTRIDE, e, __ATOMIC_RELAXED, __HIP_MEMORY_SCOPE_AGENT);
  if (bid == 0) {
    if (tid < 64) {
      for (;;) {
        bool ok = true;
#pragma unroll
        for (int i = 0; i < 4; ++i) {
          unsigned int v = __hip_atomic_load(flags + (tid + 64 * i) * FSTRIDE, __ATOMIC_RELAXED,
                                             __HIP_MEMORY_SCOPE_AGENT);
          ok &= (v >= e);
        }
        if (__all(ok)) break;
        __builtin_amdgcn_s_sleep(1);
      }
      if (tid == 0) __hip_atomic_store(rel, e, __ATOMIC_RELAXED, __HIP_MEMORY_SCOPE_AGENT);
    }
  } else if (tid == 0) {
    while (__hip_atomic_load(rel, __ATOMIC_RELAXED, __HIP_MEMORY_SCOPE_AGENT) < e)
      __builtin_amdgcn_s_sleep(1);
  }
  __syncthreads();
}

// ---------------- GEMM tile: 32(batch) x NT*16(features), K=1024 over 8 waves ----------------
// act 3-plane (stride NACT), weights NWP planes (stride bplane), plane pairs p+q<=2.
template <int NWP, int NT>
__device__ __forceinline__ void gemm_nt(const unsigned short* __restrict__ Bp, size_t bplane,
                                        const unsigned short* __restrict__ Ap, int gfbase,
                                        float* smem, f32x4 (&acc)[NT][2]) {
  const int tid = threadIdx.x;
  const int L = tid & 63, w = tid >> 6;
  const int col = L & 15, quad = L >> 4;
#pragma unroll
  for (int n = 0; n < NT; ++n) {
    acc[n][0] = {0.f, 0.f, 0.f, 0.f};
    acc[n][1] = {0.f, 0.f, 0.f, 0.f};
  }
  for (int it = 0; it < 4; ++it) {
    int k0 = w * 128 + it * 32 + quad * 8;
    bf16x8 a[3][2], b[NWP][NT];
#pragma unroll
    for (int mh = 0; mh < 2; ++mh) {
      int r = (mh * 16 + col) * HID + k0;
#pragma unroll
      for (int q = 0; q < 3; ++q) a[q][mh] = ld_act16(Ap + (size_t)q * NACT + r);
    }
#pragma unroll
    for (int n = 0; n < NT; ++n) {
      int rr = (gfbase + n * 16 + col) * HID + k0;
#pragma unroll
      for (int p = 0; p < NWP; ++p) b[p][n] = *(const bf16x8*)(Bp + (size_t)p * bplane + rr);
    }
#pragma unroll
    for (int p = 0; p < NWP; ++p)
#pragma unroll
      for (int q = 0; q < 3; ++q)
        if (p + q <= 2)
#pragma unroll
          for (int n = 0; n < NT; ++n)
#pragma unroll
            for (int mh = 0; mh < 2; ++mh) acc[n][mh] = mfma16(a[q][mh], b[p][n], acc[n][mh]);
  }
  __syncthreads();
  if (w > 0) {
    float* s = smem + ((w - 1) * 64 + L) * (NT * 8);
#pragma unroll
    for (int n = 0; n < NT; ++n) {
      *(f32x4*)(s + n * 8) = acc[n][0];
      *(f32x4*)(s + n * 8 + 4) = acc[n][1];
    }
  }
  __syncthreads();
  if (w == 0) {
#pragma unroll
    for (int sx = 0; sx < 7; ++sx) {
      const float* p = smem + (sx * 64 + L) * (NT * 8);
#pragma unroll
      for (int n = 0; n < NT; ++n) {
        acc[n][0] += *(const f32x4*)(p + n * 8);
        acc[n][1] += *(const f32x4*)(p + n * 8 + 4);
      }
    }
  }
}

// gi0 for t=0 from input x (XBP planes)
__global__ __launch_bounds__(NTHR, 2) void gi0_first(const unsigned short* __restrict__ WIHP,
                                                     const unsigned short* __restrict__ XBP,
                                                     float* __restrict__ GI) {
  __shared__ float smem[3584];
  const int tid = threadIdx.x;
  const int L = tid & 63, w = tid >> 6;
  const int col = L & 15, quad = L >> 4;
  int gf = blockIdx.x * 16;
  f32x4 acc[1][2];
  gemm_nt<3, 1>(WIHP, NWIH, XBP, gf, smem, acc);
  if (w == 0) {
#pragma unroll
    for (int mh = 0; mh < 2; ++mh)
#pragma unroll
      for (int r = 0; r < 4; ++r) {
        int b = mh * 16 + quad * 4 + r;
        st_f32(GI + (size_t)b * G3 + gf + col, acc[0][mh][r]);
      }
  }
}

// ---------------- persistent kernel: 64 x (A, P0, G1, P1, G2, P2) ----------------
__global__ __launch_bounds__(NTHR, 2) void rnn_persistent(
    const unsigned short* __restrict__ WIHP, const unsigned short* __restrict__ WHHP,
    const unsigned short* __restrict__ WXIP,
    const float* __restrict__ b_ih, const float* __restrict__ b_hh,
    const float* __restrict__ BIH0C,
    float* __restrict__ H,             // [3][NACT] fp32 (block-private slices)
    unsigned short* __restrict__ HBP,  // [3 layers][3 planes][NACT]
    float* __restrict__ GH,            // [3][32][3072]
    float* __restrict__ GI,            // [32][3072]
    unsigned short* __restrict__ HIST0, unsigned short* __restrict__ HIST1,  // [2048][1024]
    unsigned int* __restrict__ FLAGS, unsigned int* __restrict__ REL) {
  __shared__ float smem[10752];
  const int tid = threadIdx.x;
  const int L = tid & 63, w = tid >> 6;
  const int col = L & 15, quad = L >> 4;
  const int bid = blockIdx.x;
  unsigned int ep = 0;

#pragma unroll 1
  for (int t = 0; t < TSTEPS; ++t) {
    // ===== Phase A: gh0,gh1,gh2 (vs h_{t-1}) + composed gi0 (vs h2_{t-1}); NT=3 =====
    {
      int s = bid >> 6;      // 0..3
      int gf = (bid & 63) * 48;
      if (s < 3) {
        f32x4 acc[3][2];
        gemm_nt<3, 3>(WHHP + (size_t)s * LSTRIDE, NWIH, HBP + (size_t)s * 3 * NACT, gf, smem, acc);
        if (w == 0) {
          float* outp = GH + (size_t)s * (32 * G3);
#pragma unroll
          for (int n = 0; n < 3; ++n)
#pragma unroll
            for (int mh = 0; mh < 2; ++mh)
#pragma unroll
              for (int r = 0; r < 4; ++r) {
                int b = mh * 16 + quad * 4 + r;
                st_f32(outp + (size_t)b * G3 + gf + n * 16 + col, acc[n][mh][r]);
              }
        }
      } else if (t > 0) {  // t==0: gi0 precomputed by gi0_first
        f32x4 acc[3][2];
        gemm_nt<2, 3>(WXIP, WXIN, HBP + (size_t)2 * 3 * NACT, gf, smem, acc);
        if (w == 0) {
#pragma unroll
          for (int n = 0; n < 3; ++n)
#pragma unroll
            for (int mh = 0; mh < 2; ++mh)
#pragma unroll
              for (int r = 0; r < 4; ++r) {
                int b = mh * 16 + quad * 4 + r;
                st_f32(GI + (size_t)b * G3 + gf + n * 16 + col, acc[n][mh][r]);
              }
        }
      }
    }
    gbar(FLAGS, REL, ++ep);

#pragma unroll 1
    for (int l = 0; l < 3; ++l) {
      // ---- pointwise layer l (64 blocks, 1 elem/thread) ----
      if (bid < 64) {
        int jt = bid * 16;
        int b = tid >> 4, jj = tid & 15, j = jt + jj;
        const float* bi_base = (l == 0) ? ((t == 0) ? b_ih : BIH0C) : (b_ih + l * G3);
        const float* bh_base = b_hh + l * G3;
        float gi[3], gh[3];
#pragma unroll
        for (int g = 0; g < 3; ++g) {
          gi[g] = ld_f32(GI + (size_t)b * G3 + g * HID + j);
          gh[g] = ld_f32(GH + (size_t)l * (32 * G3) + (size_t)b * G3 + g * HID + j);
        }
        float ir = gi[0] + bi_base[j];
        float iz = gi[1] + bi_base[HID + j];
        float in_ = gi[2] + bi_base[2 * HID + j];
        float hr = gh[0] + bh_base[j];
        float hz = gh[1] + bh_base[HID + j];
        float hn = gh[2] + bh_base[2 * HID + j];
        float rr = 1.0f / (1.0f + expf(-(ir + hr)));
        float zz = 1.0f / (1.0f + expf(-(iz + hz)));
        float nn = tanhf(in_ + rr * hn);
        float hold = H[(size_t)l * NACT + b * HID + j];
        float hnew = (1.0f - zz) * nn + zz * hold;
        H[(size_t)l * NACT + b * HID + j] = hnew;
        unsigned short s0, s1, s2;
        split3(hnew, s0, s1, s2);
        int eidx = b * HID + j;
        unsigned short* hb = HBP + (size_t)l * 3 * NACT;
        int par = tid & 1;
        pst_plane(hb, eidx, s0, par);
        pst_plane(hb + NACT, eidx, s1, par);
        pst_plane(hb + 2 * NACT, eidx, s2, par);
        if (l == 2) {
          HIST0[(size_t)(t * BATCH + b) * HID + j] = s0;
          HIST1[(size_t)(t * BATCH + b) * HID + j] = s1;
        }
      }
      gbar(FLAGS, REL, ++ep);

      // ---- gi for layer l+1 (192 blocks, NT=1) ----
      if (l < 2) {
        if (bid < 192) {
          int gf = bid * 16;
          f32x4 acc[1][2];
          gemm_nt<3, 1>(WIHP + (size_t)(l + 1) * LSTRIDE, NWIH, HBP + (size_t)l * 3 * NACT, gf,
                        smem, acc);
          if (w == 0) {
#pragma unroll
            for (int mh = 0; mh < 2; ++mh)
#pragma unroll
              for (int r = 0; r < 4; ++r) {
                int b = mh * 16 + quad * 4 + r;
                st_f32(GI + (size_t)b * G3 + gf + col, acc[0][mh][r]);
              }
          }
        }
        gbar(FLAGS, REL, ++ep);
      }
    }
  }
}

// ---------------- deferred output GEMM: dout[2048][2500] = HIST(2pl) @ FCW(2pl)^T + fcb ------
__global__ __launch_bounds__(256) void final_fc(const unsigned short* __restrict__ H0,
                                                const unsigned short* __restrict__ H1,
                                                const unsigned short* __restrict__ FCWP,
                                                const float* __restrict__ fcb,
                                                float* __restrict__ dout) {
  int tid = threadIdx.x;
  int L = tid & 63, ws = tid >> 6;
  int col = L & 15, quad = L >> 4;
  int m0 = blockIdx.y * 64 + ws * 16;
  int jt = blockIdx.x * 64;
  f32x4 acc[4];
#pragma unroll
  for (int s = 0; s < 4; ++s) acc[s] = {0.f, 0.f, 0.f, 0.f};
  for (int kt = 0; kt < 32; ++kt) {
    int k0 = kt * 32 + quad * 8;
    bf16x8 ah = *(const bf16x8*)(H0 + (size_t)(m0 + col) * HID + k0);
    bf16x8 am = *(const bf16x8*)(H1 + (size_t)(m0 + col) * HID + k0);
    bf16x8 bh[4], bm[4];
#pragma unroll
    for (int s = 0; s < 4; ++s) {
      int jr = jt + s * 16 + col;
      int rc = jr < 2500 ? jr : 2499;
      bh[s] = *(const bf16x8*)(FCWP + (size_t)rc * HID + k0);
      bm[s] = *(const bf16x8*)(FCWP + (size_t)NFC + (size_t)rc * HID + k0);
    }
#pragma unroll
    for (int s = 0; s < 4; ++s) {
      acc[s] = mfma16(ah, bh[s], acc[s]);
      acc[s] = mfma16(ah, bm[s], acc[s]);
      acc[s] = mfma16(am, bh[s], acc[s]);
    }
  }
#pragma unroll
  for (int s = 0; s < 4; ++s) {
    int j = jt + s * 16 + col;
    if (j < 2500) {
      float bias = fcb[j];
#pragma unroll
      for (int r = 0; r < 4; ++r) {
        int R = m0 + quad * 4 + r;
        dout[(size_t)R * 2500 + j] = acc[s][r] + bias;
      }
    }
  }
}

extern "C" void kernel_launch(void* const* d_in, const int* in_sizes, int n_in,
                              void* d_out, int out_size, void* d_ws, size_t ws_size,
                              hipStream_t stream) {
  const float* x_in = (const float*)d_in[0];
  const float* W_ih = (const float*)d_in[1];
  const float* W_hh = (const float*)d_in[2];
  const float* b_ih = (const float*)d_in[3];
  const float* b_hh = (const float*)d_in[4];
  const float* fc_w = (const float*)d_in[5];
  const float* fc_b = (const float*)d_in[6];
  float* dout = (float*)d_out;
  char* ws = (char*)d_ws;

  // ---- workspace layout (bytes), with region reuse across disjoint lifetimes ----
  unsigned short* WIHP = (unsigned short*)(ws + 0);            // 56,623,104
  unsigned short* WHHP = (unsigned short*)(ws + 56623104);     // 56,623,104 -> 113,246,208
  // region C: WXIP (persistent) then FCWP (post-loop)
  unsigned short* WXIP = (unsigned short*)(ws + 113246208);    // 12,582,912 -> 125,829,120
  unsigned short* FCWP = (unsigned short*)(ws + 113246208);    // 10,240,000 (alias, after loop)
  // region D: setup scratch (PQ + WxF + WXTP) then HIST0/1 (persistent+final)
  float* Pbuf          = (float*)(ws + 125829120);             // 1,638,400
  float* Qbuf          = (float*)(ws + 127467520);             // 1,638,400
  float* WxF           = (float*)(ws + 129105920);             // 4,194,304
  unsigned short* WXTP = (unsigned short*)(ws + 133300224);    // 6,291,456 -> 139,591,680
  unsigned short* HIST0 = (unsigned short*)(ws + 125829120);   // 4,194,304 (alias)
  unsigned short* HIST1 = (unsigned short*)(ws + 130023424);   // 4,194,304 (alias)
  // state block
  float* H             = (float*)(ws + 139591680);             // 393,216
  unsigned short* HBP  = (unsigned short*)(ws + 139984896);    // 589,824
  unsigned short* XBP  = (unsigned short*)(ws + 140574720);    // 196,608
  float* GH            = (float*)(ws + 140771328);             // 1,179,648
  float* GI            = (float*)(ws + 141950976);             // 393,216
  float* CXV           = (float*)(ws + 142344192);             // 4,096
  float* CA            = (float*)(ws + 142348288);             // 6,400
  float* SA            = (float*)(ws + 142354688);             // 6,400
  float* BIH0C         = (float*)(ws + 142361088);             // 12,288
  unsigned int* FLAGS  = (unsigned int*)(ws + 142373376);      // 32,768
  unsigned int* REL    = (unsigned int*)(ws + 142406144);      // 128 -> end 142,406,272

  k_trig<<<7, 256, 0, stream>>>(CA, SA);
  for (int k0 = 0; k0 < 1024; k0 += 256) {
    k_pq<<<50, 256, 0, stream>>>(fc_w, CA, SA, Pbuf, Qbuf, k0);
    k_wx<<<1024, 256, 0, stream>>>(Pbuf, Qbuf, CA, SA, WxF, k0);
  }
  k_transpose<<<dim3(16, 16), 256, 0, stream>>>(WxF, WXTP);
  convert_weights<<<2048, 256, 0, stream>>>(W_ih, W_hh, WIHP, WHHP);
  k_compose<<<dim3(16, 48), 256, 0, stream>>>(WIHP, WXTP, WXIP);
  k_cx<<<4, 256, 0, stream>>>(fc_b, CA, SA, CXV);
  k_bih0c<<<3072, 256, 0, stream>>>(b_ih, CXV, W_ih, BIH0C);
  setup_state<<<512, 256, 0, stream>>>(x_in, H, HBP, XBP, FLAGS, REL);
  gi0_first<<<192, NTHR, 0, stream>>>(WIHP, XBP, GI);
  rnn_persistent<<<NBLK, NTHR, 0, stream>>>(WIHP, WHHP, WXIP, b_ih, b_hh, BIH0C, H, HBP,
                                            GH, GI, HIST0, HIST1, FLAGS, REL);
  convert_fcw<<<1024, 256, 0, stream>>>(fc_w, FCWP);
  final_fc<<<dim3(40, 32), 256, 0, stream>>>(HIST0, HIST1, FCWP, fc_b, dout);
}